// Round 2
// baseline (129.706 us; speedup 1.0000x reference)
//
#include <hip/hip_runtime.h>
#include <math.h>

// JacobiMachine: 1000 steps of masked 5-point Jacobi averaging on 512x512.
// x0 = exp(-50((X-.5)^2+(Y-.5)^2)) with X,Y RANDOM fields -> white spectrum.
// Step 1 explicit (handles nonzero boundary of x0); steps 2..1000 via exact
// eigendecomposition of the interior Dirichlet operator:
//   phi_m[i] = sin(m*pi*i/511),  lam_mn = 0.5*(cos(m*pi/511)+cos(n*pi/511))
// Surviving spectrum after ^999 lives in TWO corners: m,n in {1..64} (lam~+1)
// and m,n in {447..510} (lam~-1, checkerboard). Keep both: 128 modes/dim.
// Largest discarded |lam|^999 ~ 3e-18 -> truncation is exact in fp32.

#define HW 512
#define NP 128         // modes kept per dimension
#define NPOW 999.0     // remaining steps after the explicit first step

__device__ __forceinline__ int mode_of(int p) {   // p=0..127 -> m in {1..64} u {447..510}
    return (p < 64) ? (p + 1) : (p + 383);
}

// ---------------- kernels ----------------

__global__ void k_init_x0(const float* __restrict__ X, const float* __restrict__ Y,
                          float* __restrict__ x0) {
    int idx = blockIdx.x * 256 + threadIdx.x;
    float dx = X[idx] - 0.5f;
    float dy = Y[idx] - 0.5f;
    x0[idx] = expf(-50.0f * (dx * dx + dy * dy));
}

// one exact reference step: zero-pad average then boundary mask
__global__ void k_step1(const float* __restrict__ x0, float* __restrict__ x1) {
    int j = blockIdx.x * 256 + threadIdx.x;
    int i = blockIdx.y;
    float v = 0.0f;
    if (i > 0 && i < HW - 1 && j > 0 && j < HW - 1) {
        v = 0.25f * (x0[(i - 1) * HW + j] + x0[(i + 1) * HW + j] +
                     x0[i * HW + j - 1] + x0[i * HW + j + 1]);
    }
    x1[i * HW + j] = v;
}

// S[p][i] = sin(m_p*i*pi/511), fp64-built. S[p][0]=S[p][511]=0 exactly.
__global__ void k_build_S(float* __restrict__ S) {
    int i = blockIdx.x * 256 + threadIdx.x;  // 0..511
    int p = blockIdx.y;                      // 0..NP-1
    long m = (long)mode_of(p);
    long t = (m * (long)i) % 1022;           // exact arg reduction (period 2*511)
    double ang = (double)t * (M_PI / 511.0);
    S[p * HW + i] = (float)sin(ang);
}

// L[p][q] = lam^999 * (2/511)^2, lam may be negative (999 odd -> keep sign)
__global__ void k_build_L(float* __restrict__ L) {
    int q = threadIdx.x;   // 0..127
    int p = blockIdx.x;    // 0..127
    double lp = cos((double)mode_of(p) * M_PI / 511.0);
    double lq = cos((double)mode_of(q) * M_PI / 511.0);
    double lam = 0.5 * (lp + lq);
    double mag = pow(fabs(lam), NPOW);
    if (lam < 0.0) mag = -mag;
    double norm = (2.0 / 511.0) * (2.0 / 511.0);
    L[p * NP + q] = (float)(mag * norm);
}

// C1[p][j] = sum_i S[p,i] * x1[i,j]   (128x512)
__global__ void k_m1(const float* __restrict__ S, const float* __restrict__ x1,
                     float* __restrict__ C1) {
    int j = blockIdx.x * 256 + threadIdx.x;
    int p = blockIdx.y;
    float acc = 0.0f;
    #pragma unroll 8
    for (int i = 0; i < HW; i++) acc += S[p * HW + i] * x1[i * HW + j];
    C1[p * HW + j] = acc;
}

// D[p][q] = L[p][q] * sum_j C1[p,j] * S[q,j]   (128x128)
__global__ void k_m2(const float* __restrict__ C1, const float* __restrict__ S,
                     const float* __restrict__ L, float* __restrict__ D) {
    int q = threadIdx.x;                          // 0..127
    int p = blockIdx.x * blockDim.y + threadIdx.y;
    float acc = 0.0f;
    #pragma unroll 8
    for (int j = 0; j < HW; j++) acc += C1[p * HW + j] * S[q * HW + j];
    D[p * NP + q] = acc * L[p * NP + q];
}

// E[p][j] = sum_q D[p,q] * S[q,j]   (128x512)
__global__ void k_m3(const float* __restrict__ D, const float* __restrict__ S,
                     float* __restrict__ E) {
    int j = blockIdx.x * 256 + threadIdx.x;
    int p = blockIdx.y;
    float acc = 0.0f;
    #pragma unroll
    for (int q = 0; q < NP; q++) acc += D[p * NP + q] * S[q * HW + j];
    E[p * HW + j] = acc;
}

// out[i][j] = sum_p S[p,i] * E[p,j]   (512x512); boundary exact 0 via S.
__global__ void k_m4(const float* __restrict__ S, const float* __restrict__ E,
                     float* __restrict__ out) {
    int j = blockIdx.x * 256 + threadIdx.x;
    int i = blockIdx.y;
    float acc = 0.0f;
    #pragma unroll
    for (int p = 0; p < NP; p++) acc += S[p * HW + i] * E[p * HW + j];
    out[i * HW + j] = acc;
}

// ---------------- launcher ----------------

extern "C" void kernel_launch(void* const* d_in, const int* in_sizes, int n_in,
                              void* d_out, int out_size, void* d_ws, size_t ws_size,
                              hipStream_t stream) {
    const float* X = (const float*)d_in[0];
    const float* Y = (const float*)d_in[1];
    float* out = (float*)d_out;

    float* ws = (float*)d_ws;
    float* x0 = ws;                       // 512*512
    float* S  = x0 + HW * HW;             // 128*512
    float* L  = S + NP * HW;              // 128*128
    float* C1 = L + NP * NP;              // 128*512
    float* D  = C1 + NP * HW;             // 128*128
    float* E  = D + NP * NP;              // 128*512
    float* x1 = out;                      // reuse d_out as scratch; overwritten by k_m4

    k_init_x0<<<dim3(HW * HW / 256), dim3(256), 0, stream>>>(X, Y, x0);
    k_step1  <<<dim3(HW / 256, HW), dim3(256), 0, stream>>>(x0, x1);
    k_build_S<<<dim3(HW / 256, NP), dim3(256), 0, stream>>>(S);
    k_build_L<<<dim3(NP), dim3(NP), 0, stream>>>(L);
    k_m1     <<<dim3(HW / 256, NP), dim3(256), 0, stream>>>(S, x1, C1);
    k_m2     <<<dim3(NP / 2), dim3(NP, 2), 0, stream>>>(C1, S, L, D);
    k_m3     <<<dim3(HW / 256, NP), dim3(256), 0, stream>>>(D, S, E);
    k_m4     <<<dim3(HW / 256, HW), dim3(256), 0, stream>>>(S, E, out);
}

// Round 3
// 122.456 us; speedup vs baseline: 1.0592x; 1.0592x over previous
//
#include <hip/hip_runtime.h>
#include <math.h>

// JacobiMachine: 1000 steps of masked 5-point Jacobi averaging on 512x512.
// x0 = exp(-50((X-.5)^2+(Y-.5)^2)) with X,Y RANDOM fields -> white spectrum.
// Step 1 explicit (handles x0's nonzero boundary); steps 2..1000 via exact
// eigendecomposition of the interior Dirichlet operator:
//   phi_m[i] = sin(m*pi*i/511),  lam_mn = 0.5*(cos(m*pi/511)+cos(n*pi/511))
// Surviving spectrum after ^999 lives in TWO corners: m in {1..64} (lam~+1)
// and m in {447..510} (lam~-1, checkerboard). 128 modes/dim; largest
// discarded |lam|^999 ~ 3e-18 -> truncation exact in fp32.
//
// Round 3: 8 nodes -> 4 (graph-node overhead ~7us/node dominated our share).
//  k_prep : x1 (fused gaussian+stencil, into d_out) + S basis (block-ranged)
//  k_m1   : C1 = S @ x1            (4 p-rows/block, 32MB L2 traffic)
//  k_m23  : E  = (lam^999 o (C1 S^T)) @ S, fused per-p-row, D-row in LDS
//  k_m4   : out = S^T @ E          (4 i-rows/block)

#define HW 512
#define NP 128

__device__ __forceinline__ int mode_of(int p) {   // p=0..127 -> {1..64} u {447..510}
    return (p < 64) ? (p + 1) : (p + 383);
}

__device__ __forceinline__ float gauss(const float* __restrict__ X,
                                       const float* __restrict__ Y, int idx) {
    float dx = X[idx] - 0.5f, dy = Y[idx] - 0.5f;
    return expf(-50.0f * (dx * dx + dy * dy));
}

// blocks 0..1023: x1 = masked 5-point avg of gaussian field (recomputed at
// neighbors -> identical values to materializing x0, no extra array).
// blocks 1024..1279: S[p][i] = sin(m_p*i*pi/511), fp64-built; S[p][0]=S[p][511]=0.
__global__ void k_prep(const float* __restrict__ X, const float* __restrict__ Y,
                       float* __restrict__ x1, float* __restrict__ S) {
    int b = blockIdx.x, t = threadIdx.x;
    if (b < 1024) {
        int idx = b * 256 + t;
        int i = idx >> 9, j = idx & 511;
        float v = 0.0f;
        if (i > 0 && i < HW - 1 && j > 0 && j < HW - 1) {
            v = 0.25f * (gauss(X, Y, idx - HW) + gauss(X, Y, idx + HW) +
                         gauss(X, Y, idx - 1)  + gauss(X, Y, idx + 1));
        }
        x1[idx] = v;
    } else {
        int idx = (b - 1024) * 256 + t;      // 0..65535
        int p = idx >> 9, i = idx & 511;
        long m = (long)mode_of(p);
        long tt = (m * (long)i) % 1022;      // exact arg reduction (period 2*511)
        S[idx] = (float)sin((double)tt * (M_PI / 511.0));
    }
}

// C1[p][j] = sum_i S[p,i] * x1[i,j].  grid (4 j-chunks, 32 p-groups) x 128.
__global__ void k_m1(const float* __restrict__ S, const float* __restrict__ x1,
                     float* __restrict__ C1) {
    int j = blockIdx.x * 128 + threadIdx.x;
    int p0 = blockIdx.y * 4;
    float a0 = 0.f, a1 = 0.f, a2 = 0.f, a3 = 0.f;
    #pragma unroll 4
    for (int i = 0; i < HW; i++) {
        float x = x1[i * HW + j];
        a0 += S[(p0 + 0) * HW + i] * x;      // uniform -> scalar loads
        a1 += S[(p0 + 1) * HW + i] * x;
        a2 += S[(p0 + 2) * HW + i] * x;
        a3 += S[(p0 + 3) * HW + i] * x;
    }
    C1[(p0 + 0) * HW + j] = a0;
    C1[(p0 + 1) * HW + j] = a1;
    C1[(p0 + 2) * HW + j] = a2;
    C1[(p0 + 3) * HW + j] = a3;
}

// Per p-row (128 blocks x 128 threads):
//   D[q] = lam_pq^999*(2/511)^2 * sum_j C1[p,j]*S[q,j]   (thread q)
//   E[p][4t..4t+3] = sum_q D[q]*S[q][4t..4t+3]           (float4 per thread)
__global__ void k_m23(const float* __restrict__ C1, const float* __restrict__ S,
                      float* __restrict__ E) {
    __shared__ float c1row[HW];
    __shared__ float Drow[NP];
    int p = blockIdx.x, t = threadIdx.x;

    ((float4*)c1row)[t] = ((const float4*)(C1 + p * HW))[t];   // 2KB stage
    __syncthreads();

    float acc = 0.f;
    const float* Sq = S + t * HW;
    #pragma unroll 8
    for (int j = 0; j < HW; j++) acc += c1row[j] * Sq[j];

    double lp = cos((double)mode_of(p) * M_PI / 511.0);
    double lq = cos((double)mode_of(t) * M_PI / 511.0);
    double lam = 0.5 * (lp + lq);
    double mag = pow(fabs(lam), 999.0);
    if (lam < 0.0) mag = -mag;                                  // 999 odd
    Drow[t] = (float)((double)acc * mag * (2.0 / 511.0) * (2.0 / 511.0));
    __syncthreads();

    float4 e = {0.f, 0.f, 0.f, 0.f};
    #pragma unroll 8
    for (int q = 0; q < NP; q++) {
        float d = Drow[q];
        float4 s = ((const float4*)(S + q * HW))[t];
        e.x += d * s.x; e.y += d * s.y; e.z += d * s.z; e.w += d * s.w;
    }
    ((float4*)(E + p * HW))[t] = e;
}

// out[i0..i0+3][j] = sum_p S[p,i]*E[p,j].  grid (4 j-chunks, 128 i-groups) x 128.
// Boundary rows/cols come out exactly 0 because S[p][0]=S[p][511]=0.
__global__ void k_m4(const float* __restrict__ S, const float* __restrict__ E,
                     float* __restrict__ out) {
    int j = blockIdx.x * 128 + threadIdx.x;
    int i0 = blockIdx.y * 4;
    float a0 = 0.f, a1 = 0.f, a2 = 0.f, a3 = 0.f;
    #pragma unroll 4
    for (int p = 0; p < NP; p++) {
        float e = E[p * HW + j];
        const float* Sp = S + p * HW + i0;   // uniform -> scalar loads
        a0 += Sp[0] * e; a1 += Sp[1] * e; a2 += Sp[2] * e; a3 += Sp[3] * e;
    }
    out[(i0 + 0) * HW + j] = a0;
    out[(i0 + 1) * HW + j] = a1;
    out[(i0 + 2) * HW + j] = a2;
    out[(i0 + 3) * HW + j] = a3;
}

// ---------------- launcher ----------------

extern "C" void kernel_launch(void* const* d_in, const int* in_sizes, int n_in,
                              void* d_out, int out_size, void* d_ws, size_t ws_size,
                              hipStream_t stream) {
    const float* X = (const float*)d_in[0];
    const float* Y = (const float*)d_in[1];
    float* out = (float*)d_out;

    float* ws = (float*)d_ws;
    float* S  = ws;                       // 128*512
    float* C1 = S + NP * HW;              // 128*512
    float* E  = C1 + NP * HW;             // 128*512
    float* x1 = out;                      // d_out as scratch; overwritten by k_m4

    k_prep<<<dim3(1280),     dim3(256), 0, stream>>>(X, Y, x1, S);
    k_m1  <<<dim3(4, 32),    dim3(128), 0, stream>>>(S, x1, C1);
    k_m23 <<<dim3(NP),       dim3(128), 0, stream>>>(C1, S, E);
    k_m4  <<<dim3(4, 128),   dim3(128), 0, stream>>>(S, E, out);
}

// Round 4
// 108.385 us; speedup vs baseline: 1.1967x; 1.1298x over previous
//
#include <hip/hip_runtime.h>
#include <math.h>

// JacobiMachine: 1000 steps of masked 5-point Jacobi averaging on 512x512.
// x0 = exp(-50((X-.5)^2+(Y-.5)^2)) with X,Y RANDOM fields -> white spectrum.
// Step 1 explicit (handles x0's nonzero boundary); steps 2..1000 via exact
// eigendecomposition of the interior Dirichlet operator:
//   phi_m[i] = sin(m*pi*i/511),  lam_mn = 0.5*(cos(m*pi/511)+cos(n*pi/511))
// Surviving spectrum after ^999: m in {1..64} (lam~+1) and {447..510}
// (lam~-1 checkerboard). 128 modes/dim; largest discarded |lam|^999 ~ 3e-18.
//
// Round 4: k_m1 reverted to high-parallelism form. Round-3 post-mortem: the
// 4-p-rows-per-block variant had 256 waves total (1 wave/CU) and went
// latency-bound at 41us (occupancy 2.3%, VALUBusy 2%). These matmuls are
// ~0.2us of FLOPs -- wave count beats per-thread reuse.

#define HW 512
#define NP 128

__device__ __forceinline__ int mode_of(int p) {   // p=0..127 -> {1..64} u {447..510}
    return (p < 64) ? (p + 1) : (p + 383);
}

__device__ __forceinline__ float gauss(const float* __restrict__ X,
                                       const float* __restrict__ Y, int idx) {
    float dx = X[idx] - 0.5f, dy = Y[idx] - 0.5f;
    return expf(-50.0f * (dx * dx + dy * dy));
}

// blocks 0..1023: x1 = masked 5-point avg of gaussian field (recomputed at
// neighbors -> identical to materializing x0, no extra array).
// blocks 1024..1279: S[p][i] = sin(m_p*i*pi/511), fp64-built; S[p][0]=S[p][511]=0.
__global__ void k_prep(const float* __restrict__ X, const float* __restrict__ Y,
                       float* __restrict__ x1, float* __restrict__ S) {
    int b = blockIdx.x, t = threadIdx.x;
    if (b < 1024) {
        int idx = b * 256 + t;
        int i = idx >> 9, j = idx & 511;
        float v = 0.0f;
        if (i > 0 && i < HW - 1 && j > 0 && j < HW - 1) {
            v = 0.25f * (gauss(X, Y, idx - HW) + gauss(X, Y, idx + HW) +
                         gauss(X, Y, idx - 1)  + gauss(X, Y, idx + 1));
        }
        x1[idx] = v;
    } else {
        int idx = (b - 1024) * 256 + t;      // 0..65535
        int p = idx >> 9, i = idx & 511;
        long m = (long)mode_of(p);
        long tt = (m * (long)i) % 1022;      // exact arg reduction (period 2*511)
        S[idx] = (float)sin((double)tt * (M_PI / 511.0));
    }
}

// C1[p][j] = sum_i S[p,i] * x1[i,j].
// grid (2 j-chunks, 128 p) x 256 threads = 256 blocks x 4 waves = 1024 waves.
// S[p,i] is wave-uniform (scalar loads); x1 reads coalesced, L2-resident.
__global__ void k_m1(const float* __restrict__ S, const float* __restrict__ x1,
                     float* __restrict__ C1) {
    int j = blockIdx.x * 256 + threadIdx.x;
    int p = blockIdx.y;
    float acc = 0.0f;
    #pragma unroll 8
    for (int i = 0; i < HW; i++) acc += S[p * HW + i] * x1[i * HW + j];
    C1[p * HW + j] = acc;
}

// Per p-row (128 blocks x 128 threads):
//   D[q] = lam_pq^999*(2/511)^2 * sum_j C1[p,j]*S[q,j]   (thread q)
//   E[p][4t..4t+3] = sum_q D[q]*S[q][4t..4t+3]           (float4 per thread)
__global__ void k_m23(const float* __restrict__ C1, const float* __restrict__ S,
                      float* __restrict__ E) {
    __shared__ float c1row[HW];
    __shared__ float Drow[NP];
    int p = blockIdx.x, t = threadIdx.x;

    ((float4*)c1row)[t] = ((const float4*)(C1 + p * HW))[t];   // 2KB stage
    __syncthreads();

    float acc = 0.f;
    const float* Sq = S + t * HW;
    #pragma unroll 8
    for (int j = 0; j < HW; j++) acc += c1row[j] * Sq[j];

    double lp = cos((double)mode_of(p) * M_PI / 511.0);
    double lq = cos((double)mode_of(t) * M_PI / 511.0);
    double lam = 0.5 * (lp + lq);
    double mag = pow(fabs(lam), 999.0);
    if (lam < 0.0) mag = -mag;                                  // 999 odd
    Drow[t] = (float)((double)acc * mag * (2.0 / 511.0) * (2.0 / 511.0));
    __syncthreads();

    float4 e = {0.f, 0.f, 0.f, 0.f};
    #pragma unroll 8
    for (int q = 0; q < NP; q++) {
        float d = Drow[q];
        float4 s = ((const float4*)(S + q * HW))[t];
        e.x += d * s.x; e.y += d * s.y; e.z += d * s.z; e.w += d * s.w;
    }
    ((float4*)(E + p * HW))[t] = e;
}

// out[i][j] = sum_p S[p,i]*E[p,j].
// grid (2 j-chunks, 256 i) x 256 threads = 512 blocks x 4 waves.
// Boundary rows/cols come out exactly 0 because S[p][0]=S[p][511]=0.
__global__ void k_m4(const float* __restrict__ S, const float* __restrict__ E,
                     float* __restrict__ out) {
    int j = blockIdx.x * 256 + threadIdx.x;
    int i = blockIdx.y;
    float acc = 0.0f;
    #pragma unroll 8
    for (int p = 0; p < NP; p++) acc += S[p * HW + i] * E[p * HW + j];
    out[i * HW + j] = acc;
}

// ---------------- launcher ----------------

extern "C" void kernel_launch(void* const* d_in, const int* in_sizes, int n_in,
                              void* d_out, int out_size, void* d_ws, size_t ws_size,
                              hipStream_t stream) {
    const float* X = (const float*)d_in[0];
    const float* Y = (const float*)d_in[1];
    float* out = (float*)d_out;

    float* ws = (float*)d_ws;
    float* S  = ws;                       // 128*512
    float* C1 = S + NP * HW;              // 128*512
    float* E  = C1 + NP * HW;             // 128*512
    float* x1 = out;                      // d_out as scratch; overwritten by k_m4

    k_prep<<<dim3(1280),     dim3(256), 0, stream>>>(X, Y, x1, S);
    k_m1  <<<dim3(2, NP),    dim3(256), 0, stream>>>(S, x1, C1);
    k_m23 <<<dim3(NP),       dim3(128), 0, stream>>>(C1, S, E);
    k_m4  <<<dim3(2, HW),    dim3(256), 0, stream>>>(S, E, out);
}